// Round 15
// baseline (109.720 us; speedup 1.0000x reference)
//
#include <hip/hip_runtime.h>
#include <stdint.h>

// Square-attack schedule collapse for B=1, C=3, H=224, EPS=0.05, N_QUERIES=5000.
//
// R14: cooperative launch FAILED silently (out stayed zero => absmax 1.0) --
// hipLaunchCooperativeKernel not viable on this harness. R15: single PLAIN
// kernel, 294 blocks x 512. NPIX = 98*512, so block's channel c = blk/98 is
// uniform per block. Each block redundantly rebuilds its channel's 8 per-seg
// range-max tables in LDS (5000-step RNG, ~10 steps/thread; verified binning/
// tree code), computes the 224 init signs for its channel, then resolves its
// 512 pixels from LDS. No global table, no second dispatch, no inter-block
// communication. ~40 us of dur_us is the harness d_ws poison fill (fixed).
//
// RNG: JAX threefry2x32, jax_threefry_partitionable=True (verified exact):
//   fold_in(key, d)          = tf(key, (0, d))
//   split(k)                 = k1 = tf(k,(0,0)), k2 = tf(k,(0,1))
//   random_bits(key,32,n)[i] = X0 ^ X1 of tf(key, (0, i))

#define HH 224
#define NQ 5000
#define NPIX (HH * HH)      // 50176 = 98 * 512
#define EPSF 0.05f

__device__ __forceinline__ void tf2x32(uint32_t k0, uint32_t k1,
                                       uint32_t x0, uint32_t x1,
                                       uint32_t& o0, uint32_t& o1) {
  uint32_t ks2 = k0 ^ k1 ^ 0x1BD11BDAu;
  x0 += k0; x1 += k1;
#define TFR(r) { x0 += x1; x1 = (x1 << (r)) | (x1 >> (32 - (r))); x1 ^= x0; }
  TFR(13) TFR(15) TFR(26) TFR(6)
  x0 += k1;  x1 += ks2 + 1u;
  TFR(17) TFR(29) TFR(16) TFR(24)
  x0 += ks2; x1 += k0 + 2u;
  TFR(13) TFR(15) TFR(26) TFR(6)
  x0 += k0;  x1 += k1 + 3u;
  TFR(17) TFR(29) TFR(16) TFR(24)
  x0 += k1;  x1 += ks2 + 4u;
  TFR(13) TFR(15) TFR(26) TFR(6)
  x0 += ks2; x1 += k0 + 5u;
#undef TFR
  o0 = x0; o1 = x1;
}

__device__ __forceinline__ int sign_from_bits(uint32_t bits) {
  uint32_t mant = bits >> 9;
  return (mant > 0x400000u) ? 1 : ((mant < 0x400000u) ? -1 : 0);
}

__device__ __forceinline__ float u01_from_bits(uint32_t bits) {
  return __uint_as_float(0x3f800000u | (bits >> 9)) - 1.0f;
}

// static schedule (verified exact)
__device__ __forceinline__ int seg_of(int t) {
  if (t <= 10)   return 0;
  if (t <= 50)   return 1;
  if (t <= 200)  return 2;
  if (t <= 500)  return 3;
  if (t <= 1000) return 4;
  if (t <= 2000) return 5;
  if (t <= 4000) return 6;
  return 7;
}
__constant__ int SEG_SZ_C[8] = {200, 142, 100, 71, 50, 35, 25, 18};

// 294 blocks x 512. Block's channel c = blk/98 (NPIX = 98*512 exactly).
// Phase 1: redundant per-block build of this channel's 8 per-seg tables in
// LDS + 224 init signs. Phase 2: resolve 512 pixels from LDS.
__global__ __launch_bounds__(512) void fused_kernel(const float* __restrict__ x,
                                                    float* __restrict__ out) {
  __shared__ uint32_t bins[8 * 224];      // [seg][v]        7168 B
  __shared__ uint16_t tab[8 * 8 * 224];   // [seg][k][v]    28672 B
  __shared__ int8_t isign_l[224];         //                  224 B
  int blk = blockIdx.x;
  int tid = threadIdx.x;
  int c = blk / 98;                       // uniform per block
  int p = (blk - c * 98) * 512 + tid;     // pixel 0..50175

  for (int i = tid; i < 8 * 224; i += 512) bins[i] = 0;
  __syncthreads();

  // all 5000 steps, this channel's sign only (5 tf2x32 per step)
  for (int t = tid; t < NQ; t += 512) {
    uint32_t f0, f1;
    tf2x32(0u, 1u, 0u, (uint32_t)(t + 1), f0, f1);      // k = fold_in(base, t+1)
    uint32_t a0, a1, b0, b1;
    tf2x32(f0, f1, 0u, 0u, a0, a1);                     // k1 = tf(k, (0,0))
    tf2x32(f0, f1, 0u, 1u, b0, b1);                     // k2 = tf(k, (0,1))
    uint32_t u0, u1;
    tf2x32(a0, a1, 0u, 0u, u0, u1);                     // scalar uniform bits
    int seg = seg_of(t);
    int s = SEG_SZ_C[seg];
    int vh = (int)floorf(u01_from_bits(u0 ^ u1) * (float)(HH - s));
    uint32_t c0, c1;
    tf2x32(b0, b1, 0u, (uint32_t)c, c0, c1);            // this channel's sign bits
    int g = sign_from_bits(c0 ^ c1);
    if (g) atomicMax(&bins[seg * 224 + vh],
                     (((uint32_t)(t + 1)) << 1) | (uint32_t)(g > 0));
  }

  // init stripe signs for this channel: n = c*224 + j
  if (tid < 224) {
    uint32_t g0, g1;
    tf2x32(0u, 1u, 0u, 0u, g0, g1);                     // fold_in(base, 0)
    uint32_t o0, o1;
    tf2x32(g0, g1, 0u, (uint32_t)(c * 224 + tid), o0, o1);
    isign_l[tid] = (int8_t)sign_from_bits(o0 ^ o1);
  }
  __syncthreads();

  // tree level 0
  for (int i = tid; i < 8 * 224; i += 512) {
    int seg = i / 224, v = i % 224;
    tab[(seg * 8) * 224 + v] = (uint16_t)bins[i];
  }
  __syncthreads();
  for (int k = 1; k < 8; ++k) {
    int w = 1 << (k - 1);
    for (int i = tid; i < 8 * 224; i += 512) {
      int seg = i / 224, v = i % 224;
      uint16_t a = tab[(seg * 8 + k - 1) * 224 + v];
      uint16_t b = (v + w < 224) ? tab[(seg * 8 + k - 1) * 224 + v + w] : (uint16_t)0;
      tab[(seg * 8 + k) * 224 + v] = (a > b) ? a : b;
    }
    __syncthreads();
  }

  // Phase 2: resolve this thread's pixel.
  int pi = p / HH, pj = p % HH;
  int m = min(pi, pj), M = max(pi, pj);

  const int SEG_S[8] = {200, 142, 100, 71, 50, 35, 25, 18};
  uint32_t best = 0;
#pragma unroll
  for (int seg = 0; seg < 8; ++seg) {
    const int s = SEG_S[seg];
    int lo = max(0, M - s + 1);
    int hi = min(m, 223 - s);
    bool ok = (lo <= hi);
    int len = ok ? (hi - lo + 1) : 1;
    int k = 31 - __clz(len);
    int o2 = hi + 1 - (1 << k);             // >= lo >= 0 when ok; == hi when !ok
    int b = (seg * 8 + k) * 224;
    uint32_t v = max((uint32_t)tab[b + lo], (uint32_t)tab[b + o2]);
    best = max(best, ok ? v : 0u);
  }

  int sg = best ? ((best & 1u) ? 1 : -1) : (int)isign_l[pj];

  int idx = c * NPIX + p;
  float xv = x[idx];
  out[idx] = (sg > 0) ? fminf(xv + EPSF, 1.0f)
           : (sg < 0) ? fmaxf(xv - EPSF, 0.0f)
                      : fminf(fmaxf(xv, 0.0f), 1.0f);
}

extern "C" void kernel_launch(void* const* d_in, const int* in_sizes, int n_in,
                              void* d_out, int out_size, void* d_ws, size_t ws_size,
                              hipStream_t stream) {
  const float* x = (const float*)d_in[0];
  float* out = (float*)d_out;
  fused_kernel<<<294, 512, 0, stream>>>(x, out);
}